// Round 4
// baseline (345.981 us; speedup 1.0000x reference)
//
#include <hip/hip_runtime.h>
#include <hip/hip_bf16.h>

// ---------------------------------------------------------------------------
// UnimodalBranch: conv3x3/s2+bias+relu -> gather -> double CSR segment-max
//                 -> add x_3d
//   1) halo-only zero of padded input (interior written by transpose)
//   2) transpose+convert x -> xtp [B][258][2 planes][129][64] bf16
//      (u32 channel-pair packed stores, conflict-free LDS tile)
//   3) reorder weights -> wt2b [khkw][cout][ci] bf16 (contiguous B K-chunks)
//   4) implicit-GEMM conv, mfma_f32_16x16x32_bf16, 128x128 tile, BK=64,
//      512 thr / 8 waves (2x4) for occupancy, XOR-swizzled LDS,
//      global_load_lds w16, dbuf; bias+relu fused; LDS-bounced coalesced
//      epilogue stores.
//   5) fused two-level CSR segment max over contiguous row range
//      [a_ptr[v_ptr[n]], a_ptr[v_ptr[n+1]]) (values >= 0, empty -> 0).
//      ONE BLOCK (4 waves) PER POINT to kill the long-segment tail;
//      LDS max-combine. out = x_3d + max.
// ---------------------------------------------------------------------------

#define B_IMG  8
#define C_IN   64
#define H_IN   256
#define W_IN   256
#define C_OUT  128
#define OH     128
#define OW     128
#define NPIX   (B_IMG * OH * OW)     // 131072
#define KTOT   576                   // 64*9
#define N_PTS  50000

#define HP     258                   // padded H rows (ph = h+1)
#define PLANE  (129 * 64)            // 8256 elems: one even/odd column plane
#define HROW   (2 * PLANE)           // 16512 elems per padded row

typedef __bf16 bf16x8 __attribute__((ext_vector_type(8)));
typedef float  f32x4  __attribute__((ext_vector_type(4)));

typedef unsigned int __attribute__((address_space(3))) u32_lds;
typedef unsigned int __attribute__((address_space(1))) u32_glb;

#define GLOAD_LDS16(gsrc, ldst)                                                \
  __builtin_amdgcn_global_load_lds((const u32_glb*)(gsrc),                     \
                                   (u32_lds*)(ldst), 16, 0, 0)

// ws layout (bytes)
#define XTP_BYTES   (B_IMG * HP * HROW * 2)               // 68,161,536
#define G_BYTES     (NPIX * C_OUT * 2)                    // 33,554,432
#define XTP_OFF     0
#define G_OFF       XTP_BYTES
#define WT2_OFF     (XTP_BYTES + G_BYTES)

// ---------------------------------------------------------------------------
// zero ONLY the halo: rows ph=0,257 fully; cols pc=0 (plane0,w2=0) and
// pc=257 (plane1,w2=128) for interior rows. ~1 MB total.
__global__ __launch_bounds__(256) void halo_zero_kernel(__hip_bfloat16* __restrict__ xtp) {
  const int ph = blockIdx.x;          // 0..257
  const int b  = blockIdx.y;
  const int tid = threadIdx.x;
  const long base = ((long)b * HP + ph) * HROW;   // elems (even)
  uint4 z = make_uint4(0u, 0u, 0u, 0u);
  uint4* p = (uint4*)(xtp + base);
  if (ph == 0 || ph == HP - 1) {
    for (int i = tid; i < (HROW * 2) / 16; i += 256) p[i] = z;   // 2064 uint4
  } else {
    if (tid < 8) p[tid] = z;                                      // pc=0: elems 0..63
    else if (tid < 16) ((uint4*)(xtp + base + PLANE + 128 * 64))[tid - 8] = z; // pc=257
  }
}

// x [B][Ci][H][W] f32 -> xtp [B][258][2][129][64] bf16 (pc = w+1; plane pc&1)
// channel-pair u32 packing; LDS tile [cpair][w] with %32-friendly stride 65.
__global__ __launch_bounds__(256) void transpose_x_kernel(
    const float* __restrict__ x, unsigned* __restrict__ xtp32) {
  __shared__ unsigned tile32[32][65];   // bank = (cpair + w) % 32 -> 2-way max
  const int tid = threadIdx.x;
  const int w0  = blockIdx.x * 64;
  const int h   = blockIdx.y;
  const int b   = blockIdx.z;

  const int wl = tid & 63;
  const int c4 = tid >> 6;              // 0..3
  for (int cc = 0; cc < 8; ++cc) {
    int cpair = cc * 4 + c4;            // 0..31
    const float* xr = x + (((long)(b * C_IN + 2 * cpair) * H_IN) + h) * W_IN + w0;
    float v0 = xr[wl];
    float v1 = xr[(long)H_IN * W_IN + wl];
    unsigned u0 = __builtin_bit_cast(unsigned short, (__bf16)v0);
    unsigned u1 = __builtin_bit_cast(unsigned short, (__bf16)v1);
    tile32[cpair][wl] = u0 | (u1 << 16);
  }
  __syncthreads();
  const int cpair = tid & 31;
  const int ws0   = tid >> 5;           // 0..7
  const long rowb2 = (((long)(b * HP) + h + 1) * HROW) >> 1;   // u32 index
  for (int it = 0; it < 8; ++it) {
    int wloc = it * 8 + ws0;
    int pc   = w0 + wloc + 1;
    xtp32[rowb2 + (pc & 1) * (PLANE >> 1) + (pc >> 1) * 32 + cpair] =
        tile32[cpair][wloc];
  }
}

// w [cout][ci][3][3] f32 -> wt2b [khkw][cout][ci] bf16
__global__ __launch_bounds__(256) void wprep_kernel(
    const float* __restrict__ w, __hip_bfloat16* __restrict__ wt2b) {
  int tid  = blockIdx.x * 256 + threadIdx.x;   // 0 .. 73727
  int khkw = tid >> 13;
  int cout = (tid >> 6) & 127;
  int ci   = tid & 63;
  wt2b[tid] = (__hip_bfloat16)w[(cout * C_IN + ci) * 9 + khkw];
}

// ---------------------------------------------------------------------------
// implicit-GEMM conv: tile 128 pixels x 128 cout, K=576, BK=64 (9 chunks).
// block = 512 thr (8 waves, 2x4): wave tile 64 pix x 32 cout.
// LDS A/B 16KB each double-buffered (64KB) -> 2 blocks/CU = 4 waves/SIMD.
// Chunk sources fully contiguous 16KB; XOR chunk-swizzle via pre-swizzled
// global source + swizzled ds_read (rule #21).
__global__ __launch_bounds__(512) void conv_gemm_kernel(
    const __hip_bfloat16* __restrict__ xtp,
    const __hip_bfloat16* __restrict__ wt2b,
    const float* __restrict__ bias,
    __hip_bfloat16* __restrict__ g) {
  __shared__ __hip_bfloat16 Abuf[2][8192];
  __shared__ __hip_bfloat16 Bbuf[2][8192];

  const int tid  = threadIdx.x;
  const int lane = tid & 63;
  const int wid  = tid >> 6;            // 0..7
  const int bid  = blockIdx.x;          // 0..1023 = bimg*128 + oh
  const int bimg = bid >> 7;
  const int oh   = bid & 127;
  const int wr   = wid >> 2;            // 0..1  (64-pixel row block)
  const int wc   = wid & 3;             // 0..3  (32-cout col block)

  f32x4 acc[4][2] = {};

  auto stage = [&](int buf, int t) {
    const int kh = t / 3;
    const int kw = t - kh * 3;
    const long abase = (((long)bimg * HP + (2 * oh + kh)) * 2 + (kw & 1)) * PLANE
                       + ((kw == 2) ? 64 : 0);
    const long bbase = (long)t * 8192;
    for (int p = 0; p < 2; ++p) {
      int flat = p * 512 + tid;
      int row  = flat >> 3;                       // 0..127
      int cs   = (flat & 7) ^ (row & 7);          // inverse-swizzled src chunk
      long soff = (long)row * 64 + cs * 8;
      char* dA = (char*)&Abuf[buf][0] + flat * 16;
      char* dB = (char*)&Bbuf[buf][0] + flat * 16;
      GLOAD_LDS16(xtp + abase + soff, dA);
      GLOAD_LDS16(wt2b + bbase + soff, dB);
    }
  };

  auto compute = [&](int buf) {
    const int r15 = lane & 15;
    const int kg  = lane >> 4;
    for (int h = 0; h < 2; ++h) {
      bf16x8 af[4], bfv[2];
      const int co = h * 4 + kg;
      for (int i = 0; i < 4; ++i) {
        int rowa = wr * 64 + i * 16 + r15;
        int ca   = co ^ (rowa & 7);
        af[i] = *(const bf16x8*)((const char*)&Abuf[buf][0] + rowa * 128 + ca * 16);
      }
      for (int n = 0; n < 2; ++n) {
        int rowb = wc * 32 + n * 16 + r15;
        int cb   = co ^ (rowb & 7);
        bfv[n] = *(const bf16x8*)((const char*)&Bbuf[buf][0] + rowb * 128 + cb * 16);
      }
      for (int i = 0; i < 4; ++i)
        for (int n = 0; n < 2; ++n)
          acc[i][n] = __builtin_amdgcn_mfma_f32_16x16x32_bf16(af[i], bfv[n],
                                                              acc[i][n], 0, 0, 0);
    }
  };

  stage(0, 0);
  __syncthreads();
  int cur = 0;
  for (int t = 0; t < 9; ++t) {
    if (t + 1 < 9) stage(cur ^ 1, t + 1);
    compute(cur);
    __syncthreads();
    cur ^= 1;
  }

  // epilogue: bias+relu -> LDS bf16 C-tile -> coalesced dwordx4 stores
  __hip_bfloat16* ct = &Abuf[0][0];               // 32KB = both A buffers
  const int col0 = wc * 32 + (lane & 15);
  float bn[2];
  for (int n = 0; n < 2; ++n) bn[n] = bias[col0 + n * 16];
  for (int i = 0; i < 4; ++i) {
    int row0 = wr * 64 + i * 16 + (lane >> 4) * 4;
    for (int n = 0; n < 2; ++n) {
      int cout = col0 + n * 16;
      for (int r = 0; r < 4; ++r) {
        float v = fmaxf(acc[i][n][r] + bn[n], 0.0f);
        ct[(row0 + r) * 128 + cout] = (__hip_bfloat16)v;
      }
    }
  }
  __syncthreads();
  const long gbase = (long)bid * (128 * 128);
  for (int it = 0; it < 4; ++it) {
    int flat = it * 512 + tid;
    bf16x8 v = *(const bf16x8*)((const char*)ct + flat * 16);
    *(bf16x8*)(g + gbase + (long)flat * 8) = v;
  }
}

// ---------------------------------------------------------------------------
// fused two-level CSR segment-max + add. ONE BLOCK (4 waves) PER POINT:
// waves split the row range (tail-parallel), LDS max-combine.
// Per wave: batch-load 64 indices coalesced; each lane reads 16B (8 ch)
// so one load covers 4 rows; 2 quads in flight per inner iter.
__global__ __launch_bounds__(256) void gather_max_add_kernel(
    const __hip_bfloat16* __restrict__ g,
    const float* __restrict__ x3d,
    const int* __restrict__ fm_idx,
    const int* __restrict__ a_ptr,
    const int* __restrict__ v_ptr,
    float* __restrict__ out) {
  __shared__ float red[4][128];
  const int tid  = threadIdx.x;
  const int lane = tid & 63;
  const int wid  = tid >> 6;
  const int n    = blockIdx.x;

  const int v0 = v_ptr[n];
  const int v1 = v_ptr[n + 1];
  const int r0 = a_ptr[v0];
  const int r1 = a_ptr[v1];
  const int len = r1 - r0;

  const int sub  = lane >> 4;     // row-in-quad 0..3
  const int ch16 = lane & 15;     // 16B chunk = channels ch16*8 .. +7

  float m[8];
#pragma unroll
  for (int k = 0; k < 8; ++k) m[k] = 0.0f;

  const uint4* gp = (const uint4*)g;

  for (int base = wid * 64; base < len; base += 256) {
    int nb = len - base;
    if (nb > 64) nb = 64;
    int li = base + lane;
    if (li >= len) li = len - 1;
    const int idx_l = fm_idx[r0 + li];           // one coalesced batch load

    for (int j = 0; j < nb; j += 8) {
      int ra = j + sub;
      int rb = j + 4 + sub;
      if (ra >= nb) ra = nb - 1;                 // duplicate row: max-safe
      if (rb >= nb) rb = nb - 1;
      int ia = __shfl(idx_l, ra);
      int ib = __shfl(idx_l, rb);
      uint4 va = gp[(long)ia * 16 + ch16];
      uint4 vb = gp[(long)ib * 16 + ch16];
      const unsigned* ua = (const unsigned*)&va;
      const unsigned* ub = (const unsigned*)&vb;
#pragma unroll
      for (int w = 0; w < 4; ++w) {
        m[2 * w]     = fmaxf(m[2 * w],     __uint_as_float(ua[w] << 16));
        m[2 * w + 1] = fmaxf(m[2 * w + 1], __uint_as_float(ua[w] & 0xffff0000u));
        m[2 * w]     = fmaxf(m[2 * w],     __uint_as_float(ub[w] << 16));
        m[2 * w + 1] = fmaxf(m[2 * w + 1], __uint_as_float(ub[w] & 0xffff0000u));
      }
    }
  }

  // combine the 4 row-subgroups (same channels live at lane^16, lane^32)
#pragma unroll
  for (int k = 0; k < 8; ++k) {
    m[k] = fmaxf(m[k], __shfl_xor(m[k], 16));
    m[k] = fmaxf(m[k], __shfl_xor(m[k], 32));
  }
  if (sub == 0) {
#pragma unroll
    for (int k = 0; k < 8; ++k) red[wid][ch16 * 8 + k] = m[k];
  }
  __syncthreads();

  if (tid < 128) {
    float v = fmaxf(fmaxf(red[0][tid], red[1][tid]),
                    fmaxf(red[2][tid], red[3][tid]));
    out[(long)n * 128 + tid] = x3d[(long)n * 128 + tid] + v;
  }
}

// ---------------------------------------------------------------------------
extern "C" void kernel_launch(void* const* d_in, const int* in_sizes, int n_in,
                              void* d_out, int out_size, void* d_ws, size_t ws_size,
                              hipStream_t stream) {
  const float* x     = (const float*)d_in[0];
  const float* w     = (const float*)d_in[1];
  const float* bias  = (const float*)d_in[2];
  const float* x3d   = (const float*)d_in[3];
  const int*   fmidx = (const int*)d_in[4];
  const int*   aptr  = (const int*)d_in[5];
  const int*   vptr  = (const int*)d_in[6];
  float* out = (float*)d_out;

  char* ws = (char*)d_ws;
  __hip_bfloat16* xtp  = (__hip_bfloat16*)(ws + XTP_OFF);
  __hip_bfloat16* g    = (__hip_bfloat16*)(ws + G_OFF);
  __hip_bfloat16* wt2b = (__hip_bfloat16*)(ws + WT2_OFF);

  hipLaunchKernelGGL(halo_zero_kernel, dim3(HP, B_IMG), dim3(256), 0, stream,
                     xtp);
  hipLaunchKernelGGL(transpose_x_kernel, dim3(W_IN / 64, H_IN, B_IMG), dim3(256),
                     0, stream, x, (unsigned*)xtp);
  hipLaunchKernelGGL(wprep_kernel, dim3((C_OUT * KTOT) / 256), dim3(256), 0,
                     stream, w, wt2b);
  hipLaunchKernelGGL(conv_gemm_kernel, dim3(NPIX / 128), dim3(512), 0, stream,
                     xtp, wt2b, bias, g);
  hipLaunchKernelGGL(gather_max_add_kernel, dim3(N_PTS), dim3(256), 0,
                     stream, g, x3d, fmidx, aptr, vptr, out);
}

// Round 7
// 303.755 us; speedup vs baseline: 1.1390x; 1.1390x over previous
//
#include <hip/hip_runtime.h>
#include <hip/hip_bf16.h>

// ---------------------------------------------------------------------------
// UnimodalBranch: conv3x3/s2+bias+relu -> gather -> double CSR segment-max
//                 -> add x_3d
//   1) halo-only zero of padded input (interior written by transpose)
//   2) transpose+convert x -> xtp [B][258][2 planes][129][64] bf16
//   3) reorder weights -> wt2b [khkw][cout][ci] bf16
//   4) implicit-GEMM conv, mfma 16x16x32 bf16, 128x128 tile, BK=64, 256 thr,
//      dbuf LDS + COUNTED vmcnt(8) (T4: loads in flight across barriers,
//      never drain to 0 mid-loop) + XCD-chunked block swizzle (T1).
//   5) fused two-level CSR segment max over contiguous row range
//      [a_ptr[v_ptr[n]], a_ptr[v_ptr[n+1]]) (values >= 0, empty -> 0).
//      One wave per point (R3 proven structure), 4 gathers in flight.
// ---------------------------------------------------------------------------

#define B_IMG  8
#define C_IN   64
#define H_IN   256
#define W_IN   256
#define C_OUT  128
#define OH     128
#define OW     128
#define NPIX   (B_IMG * OH * OW)     // 131072
#define KTOT   576                   // 64*9
#define N_PTS  50000

#define HP     258                   // padded H rows (ph = h+1)
#define PLANE  (129 * 64)            // 8256 elems: one even/odd column plane
#define HROW   (2 * PLANE)           // 16512 elems per padded row

typedef __bf16 bf16x8 __attribute__((ext_vector_type(8)));
typedef float  f32x4  __attribute__((ext_vector_type(4)));

typedef unsigned int __attribute__((address_space(3))) u32_lds;
typedef unsigned int __attribute__((address_space(1))) u32_glb;

#define GLOAD_LDS16(gsrc, ldst)                                                \
  __builtin_amdgcn_global_load_lds((const u32_glb*)(gsrc),                     \
                                   (u32_lds*)(ldst), 16, 0, 0)

// ws layout (bytes)
#define XTP_BYTES   (B_IMG * HP * HROW * 2)               // 68,161,536
#define G_BYTES     (NPIX * C_OUT * 2)                    // 33,554,432
#define XTP_OFF     0
#define G_OFF       XTP_BYTES
#define WT2_OFF     (XTP_BYTES + G_BYTES)

// ---------------------------------------------------------------------------
// zero ONLY the halo: rows ph=0,257 fully; cols pc=0 (plane0,w2=0) and
// pc=257 (plane1,w2=128) for interior rows. ~1 MB total.
__global__ __launch_bounds__(256) void halo_zero_kernel(__hip_bfloat16* __restrict__ xtp) {
  const int ph = blockIdx.x;          // 0..257
  const int b  = blockIdx.y;
  const int tid = threadIdx.x;
  const long base = ((long)b * HP + ph) * HROW;   // elems (even)
  uint4 z = make_uint4(0u, 0u, 0u, 0u);
  uint4* p = (uint4*)(xtp + base);
  if (ph == 0 || ph == HP - 1) {
    for (int i = tid; i < (HROW * 2) / 16; i += 256) p[i] = z;   // 2064 uint4
  } else {
    if (tid < 8) p[tid] = z;                                      // pc=0
    else if (tid < 16) ((uint4*)(xtp + base + PLANE + 128 * 64))[tid - 8] = z; // pc=257
  }
}

// x [B][Ci][H][W] f32 -> xtp [B][258][2][129][64] bf16 (pc = w+1; plane pc&1)
// channel-pair u32 packing; LDS tile [cpair][w] stride 65.
__global__ __launch_bounds__(256) void transpose_x_kernel(
    const float* __restrict__ x, unsigned* __restrict__ xtp32) {
  __shared__ unsigned tile32[32][65];
  const int tid = threadIdx.x;
  const int w0  = blockIdx.x * 64;
  const int h   = blockIdx.y;
  const int b   = blockIdx.z;

  const int wl = tid & 63;
  const int c4 = tid >> 6;              // 0..3
  for (int cc = 0; cc < 8; ++cc) {
    int cpair = cc * 4 + c4;            // 0..31
    const float* xr = x + (((long)(b * C_IN + 2 * cpair) * H_IN) + h) * W_IN + w0;
    float v0 = xr[wl];
    float v1 = xr[(long)H_IN * W_IN + wl];
    unsigned u0 = __builtin_bit_cast(unsigned short, (__bf16)v0);
    unsigned u1 = __builtin_bit_cast(unsigned short, (__bf16)v1);
    tile32[cpair][wl] = u0 | (u1 << 16);
  }
  __syncthreads();
  const int cpair = tid & 31;
  const int ws0   = tid >> 5;           // 0..7
  const long rowb2 = (((long)(b * HP) + h + 1) * HROW) >> 1;   // u32 index
  for (int it = 0; it < 8; ++it) {
    int wloc = it * 8 + ws0;
    int pc   = w0 + wloc + 1;
    xtp32[rowb2 + (pc & 1) * (PLANE >> 1) + (pc >> 1) * 32 + cpair] =
        tile32[cpair][wloc];
  }
}

// w [cout][ci][3][3] f32 -> wt2b [khkw][cout][ci] bf16
__global__ __launch_bounds__(256) void wprep_kernel(
    const float* __restrict__ w, __hip_bfloat16* __restrict__ wt2b) {
  int tid  = blockIdx.x * 256 + threadIdx.x;   // 0 .. 73727
  int khkw = tid >> 13;
  int cout = (tid >> 6) & 127;
  int ci   = tid & 63;
  wt2b[tid] = (__hip_bfloat16)w[(cout * C_IN + ci) * 9 + khkw];
}

// ---------------------------------------------------------------------------
// implicit-GEMM conv: tile 128 pixels x 128 cout, K=576, BK=64 (9 chunks).
// block = 256 thr (4 waves, 2x2): wave tile 64x64, acc[4][4].
// dbuf LDS 64KB; counted vmcnt: stage t+1 issued one iter ahead, wait
// vmcnt(8) (only chunk t's 8 loads) before raw s_barrier. vmcnt(0) only at
// the final chunk. XCD-chunked swizzle: blockIdx%8 = XCD gets contiguous oh.
__global__ __launch_bounds__(256) void conv_gemm_kernel(
    const __hip_bfloat16* __restrict__ xtp,
    const __hip_bfloat16* __restrict__ wt2b,
    const float* __restrict__ bias,
    __hip_bfloat16* __restrict__ g) {
  __shared__ __hip_bfloat16 Abuf[2][8192];
  __shared__ __hip_bfloat16 Bbuf[2][8192];

  const int tid  = threadIdx.x;
  const int lane = tid & 63;
  const int wid  = tid >> 6;
  const int b0   = blockIdx.x;                  // 0..1023
  const int bid  = (b0 & 7) * 128 + (b0 >> 3);  // XCD-chunked (bijective)
  const int bimg = bid >> 7;
  const int oh   = bid & 127;
  const int wr   = wid >> 1;
  const int wc   = wid & 1;

  f32x4 acc[4][4] = {};

  auto stage = [&](int buf, int t) {
    const int kh = t / 3;
    const int kw = t - kh * 3;
    const long abase = (((long)bimg * HP + (2 * oh + kh)) * 2 + (kw & 1)) * PLANE
                       + ((kw == 2) ? 64 : 0);
    const long bbase = (long)t * 8192;
#pragma unroll
    for (int p = 0; p < 4; ++p) {
      int flat = p * 256 + tid;
      int row  = flat >> 3;                       // 0..127
      int cs   = (flat & 7) ^ (row & 7);          // inverse-swizzled src chunk
      long soff = (long)row * 64 + cs * 8;
      char* dA = (char*)&Abuf[buf][0] + flat * 16;
      char* dB = (char*)&Bbuf[buf][0] + flat * 16;
      GLOAD_LDS16(xtp + abase + soff, dA);
      GLOAD_LDS16(wt2b + bbase + soff, dB);
    }
  };

  auto compute = [&](int buf) {
    const int r15 = lane & 15;
    const int kg  = lane >> 4;
#pragma unroll
    for (int h = 0; h < 2; ++h) {
      bf16x8 af[4], bfv[4];
      const int co = h * 4 + kg;
#pragma unroll
      for (int i = 0; i < 4; ++i) {
        int rowa = wr * 64 + i * 16 + r15;
        int ca   = co ^ (rowa & 7);
        af[i] = *(const bf16x8*)((const char*)&Abuf[buf][0] + rowa * 128 + ca * 16);
        int rowb = wc * 64 + i * 16 + r15;
        int cb   = co ^ (rowb & 7);
        bfv[i] = *(const bf16x8*)((const char*)&Bbuf[buf][0] + rowb * 128 + cb * 16);
      }
#pragma unroll
      for (int i = 0; i < 4; ++i)
#pragma unroll
        for (int n = 0; n < 4; ++n)
          acc[i][n] = __builtin_amdgcn_mfma_f32_16x16x32_bf16(af[i], bfv[n],
                                                              acc[i][n], 0, 0, 0);
    }
  };

  stage(0, 0);                                   // 8 loads
  stage(1, 1);                                   // 8 loads (16 outstanding)
#pragma unroll 1
  for (int t = 0; t < 9; ++t) {
    if (t < 8) {
      asm volatile("s_waitcnt vmcnt(8)" ::: "memory");   // chunk t landed
    } else {
      asm volatile("s_waitcnt vmcnt(0)" ::: "memory");
    }
    __builtin_amdgcn_sched_barrier(0);
    __builtin_amdgcn_s_barrier();                 // all waves' chunk-t in LDS
    compute(t & 1);
    __builtin_amdgcn_s_barrier();                 // all reads of this buf done
    __builtin_amdgcn_sched_barrier(0);
    if (t + 2 < 9) stage(t & 1, t + 2);           // refill freed buffer
  }

  // epilogue: bias+relu -> LDS bf16 C-tile -> coalesced dwordx4 stores
  __hip_bfloat16* ct = &Abuf[0][0];               // 32KB = both A buffers
  const int col0 = wc * 64 + (lane & 15);
  float bn[4];
  for (int n = 0; n < 4; ++n) bn[n] = bias[col0 + n * 16];
  for (int i = 0; i < 4; ++i) {
    int row0 = wr * 64 + i * 16 + (lane >> 4) * 4;
    for (int n = 0; n < 4; ++n) {
      int cout = col0 + n * 16;
      for (int r = 0; r < 4; ++r) {
        float v = fmaxf(acc[i][n][r] + bn[n], 0.0f);
        ct[(row0 + r) * 128 + cout] = (__hip_bfloat16)v;
      }
    }
  }
  __syncthreads();
  const long gbase = (long)bid * (128 * 128);
  for (int it = 0; it < 8; ++it) {
    int flat = it * 256 + tid;
    bf16x8 v = *(const bf16x8*)((const char*)ct + flat * 16);
    *(bf16x8*)(g + gbase + (long)flat * 8) = v;
  }
}

// ---------------------------------------------------------------------------
// fused two-level CSR segment-max + add (R3 structure, deeper ILP).
// one wave per point n. Batch-load 64 indices coalesced; each lane reads
// 16B (8 channels) so one load covers 4 rows; 4 quads (16 rows) in flight.
__global__ __launch_bounds__(256) void gather_max_add_kernel(
    const __hip_bfloat16* __restrict__ g,
    const float* __restrict__ x3d,
    const int* __restrict__ fm_idx,
    const int* __restrict__ a_ptr,
    const int* __restrict__ v_ptr,
    float* __restrict__ out) {
  const int lane = threadIdx.x & 63;
  const int n    = blockIdx.x * 4 + (threadIdx.x >> 6);

  const int v0 = v_ptr[n];
  const int v1 = v_ptr[n + 1];
  const int r0 = a_ptr[v0];
  const int r1 = a_ptr[v1];
  const int len = r1 - r0;

  const int sub  = lane >> 4;     // row-in-quad 0..3
  const int ch16 = lane & 15;     // 16B chunk = channels ch16*8 .. +7

  // hoist x3d read (overlaps with gather latency)
  const float4* x4 = (const float4*)x3d;
  const long b0 = (long)n * 32 + ch16 * 2;
  float4 xa, xb;
  if (sub == 0) { xa = x4[b0]; xb = x4[b0 + 1]; }

  float m[8];
#pragma unroll
  for (int k = 0; k < 8; ++k) m[k] = 0.0f;

  const uint4* gp = (const uint4*)g;

  for (int base = 0; base < len; base += 64) {
    int nb = len - base;
    if (nb > 64) nb = 64;
    int li = base + lane;
    if (li >= len) li = len - 1;
    const int idx_l = fm_idx[r0 + li];           // one coalesced batch load

    for (int j = 0; j < nb; j += 16) {
      int r[4];
#pragma unroll
      for (int q = 0; q < 4; ++q) {
        int rr = j + q * 4 + sub;
        r[q] = (rr >= nb) ? nb - 1 : rr;         // duplicate row: max-safe
      }
      uint4 v[4];
#pragma unroll
      for (int q = 0; q < 4; ++q) {
        int iq = __shfl(idx_l, r[q]);
        v[q] = gp[(long)iq * 16 + ch16];
      }
#pragma unroll
      for (int q = 0; q < 4; ++q) {
        const unsigned* u = (const unsigned*)&v[q];
#pragma unroll
        for (int w = 0; w < 4; ++w) {
          m[2 * w]     = fmaxf(m[2 * w],     __uint_as_float(u[w] << 16));
          m[2 * w + 1] = fmaxf(m[2 * w + 1], __uint_as_float(u[w] & 0xffff0000u));
        }
      }
    }
  }

  // combine the 4 row-subgroups (same channels live at lane^16, lane^32)
#pragma unroll
  for (int k = 0; k < 8; ++k) {
    m[k] = fmaxf(m[k], __shfl_xor(m[k], 16));
    m[k] = fmaxf(m[k], __shfl_xor(m[k], 32));
  }

  if (sub == 0) {
    float4* o4 = (float4*)out;
    float4 oa, ob;
    oa.x = xa.x + m[0]; oa.y = xa.y + m[1]; oa.z = xa.z + m[2]; oa.w = xa.w + m[3];
    ob.x = xb.x + m[4]; ob.y = xb.y + m[5]; ob.z = xb.z + m[6]; ob.w = xb.w + m[7];
    o4[b0]     = oa;
    o4[b0 + 1] = ob;
  }
}

// ---------------------------------------------------------------------------
extern "C" void kernel_launch(void* const* d_in, const int* in_sizes, int n_in,
                              void* d_out, int out_size, void* d_ws, size_t ws_size,
                              hipStream_t stream) {
  const float* x     = (const float*)d_in[0];
  const float* w     = (const float*)d_in[1];
  const float* bias  = (const float*)d_in[2];
  const float* x3d   = (const float*)d_in[3];
  const int*   fmidx = (const int*)d_in[4];
  const int*   aptr  = (const int*)d_in[5];
  const int*   vptr  = (const int*)d_in[6];
  float* out = (float*)d_out;

  char* ws = (char*)d_ws;
  __hip_bfloat16* xtp  = (__hip_bfloat16*)(ws + XTP_OFF);
  __hip_bfloat16* g    = (__hip_bfloat16*)(ws + G_OFF);
  __hip_bfloat16* wt2b = (__hip_bfloat16*)(ws + WT2_OFF);

  hipLaunchKernelGGL(halo_zero_kernel, dim3(HP, B_IMG), dim3(256), 0, stream,
                     xtp);
  hipLaunchKernelGGL(transpose_x_kernel, dim3(W_IN / 64, H_IN, B_IMG), dim3(256),
                     0, stream, x, (unsigned*)xtp);
  hipLaunchKernelGGL(wprep_kernel, dim3((C_OUT * KTOT) / 256), dim3(256), 0,
                     stream, w, wt2b);
  hipLaunchKernelGGL(conv_gemm_kernel, dim3(NPIX / 128), dim3(256), 0, stream,
                     xtp, wt2b, bias, g);
  hipLaunchKernelGGL(gather_max_add_kernel, dim3(N_PTS / 4), dim3(256), 0,
                     stream, g, x3d, fmidx, aptr, vptr, out);
}

// Round 8
// 301.097 us; speedup vs baseline: 1.1491x; 1.0088x over previous
//
#include <hip/hip_runtime.h>
#include <hip/hip_bf16.h>

// ---------------------------------------------------------------------------
// UnimodalBranch: conv3x3/s2+bias+relu -> gather -> double CSR segment-max
//                 -> add x_3d
//   1) halo-only zero of padded input (interior written by transpose)
//   2) transpose+convert x -> xtp [B][258][2 planes][129][64] bf16
//   3) reorder weights -> wt2b [khkw][cout][ci] bf16
//   4) implicit-GEMM conv, mfma 16x16x32 bf16, 128x128 tile, BK=64,
//      512 thr / 8 waves (4x2, wave-tile 32x64) -> 16 waves/CU for TLP,
//      dbuf LDS + counted vmcnt(4) + XCD-chunked block swizzle.
//   5) fused two-level CSR segment max over contiguous row range
//      [a_ptr[v_ptr[n]], a_ptr[v_ptr[n+1]]) (values >= 0, empty -> 0).
//      One wave per point, 4 gathers in flight.
// ---------------------------------------------------------------------------

#define B_IMG  8
#define C_IN   64
#define H_IN   256
#define W_IN   256
#define C_OUT  128
#define OH     128
#define OW     128
#define NPIX   (B_IMG * OH * OW)     // 131072
#define KTOT   576                   // 64*9
#define N_PTS  50000

#define HP     258                   // padded H rows (ph = h+1)
#define PLANE  (129 * 64)            // 8256 elems: one even/odd column plane
#define HROW   (2 * PLANE)           // 16512 elems per padded row

typedef __bf16 bf16x8 __attribute__((ext_vector_type(8)));
typedef float  f32x4  __attribute__((ext_vector_type(4)));

typedef unsigned int __attribute__((address_space(3))) u32_lds;
typedef unsigned int __attribute__((address_space(1))) u32_glb;

#define GLOAD_LDS16(gsrc, ldst)                                                \
  __builtin_amdgcn_global_load_lds((const u32_glb*)(gsrc),                     \
                                   (u32_lds*)(ldst), 16, 0, 0)

// ws layout (bytes)
#define XTP_BYTES   (B_IMG * HP * HROW * 2)               // 68,161,536
#define G_BYTES     (NPIX * C_OUT * 2)                    // 33,554,432
#define XTP_OFF     0
#define G_OFF       XTP_BYTES
#define WT2_OFF     (XTP_BYTES + G_BYTES)

// ---------------------------------------------------------------------------
// zero ONLY the halo: rows ph=0,257 fully; cols pc=0 (plane0,w2=0) and
// pc=257 (plane1,w2=128) for interior rows. ~1 MB total.
__global__ __launch_bounds__(256) void halo_zero_kernel(__hip_bfloat16* __restrict__ xtp) {
  const int ph = blockIdx.x;          // 0..257
  const int b  = blockIdx.y;
  const int tid = threadIdx.x;
  const long base = ((long)b * HP + ph) * HROW;   // elems (even)
  uint4 z = make_uint4(0u, 0u, 0u, 0u);
  uint4* p = (uint4*)(xtp + base);
  if (ph == 0 || ph == HP - 1) {
    for (int i = tid; i < (HROW * 2) / 16; i += 256) p[i] = z;   // 2064 uint4
  } else {
    if (tid < 8) p[tid] = z;                                      // pc=0
    else if (tid < 16) ((uint4*)(xtp + base + PLANE + 128 * 64))[tid - 8] = z; // pc=257
  }
}

// x [B][Ci][H][W] f32 -> xtp [B][258][2][129][64] bf16 (pc = w+1; plane pc&1)
// channel-pair u32 packing; LDS tile [cpair][w] stride 65.
__global__ __launch_bounds__(256) void transpose_x_kernel(
    const float* __restrict__ x, unsigned* __restrict__ xtp32) {
  __shared__ unsigned tile32[32][65];
  const int tid = threadIdx.x;
  const int w0  = blockIdx.x * 64;
  const int h   = blockIdx.y;
  const int b   = blockIdx.z;

  const int wl = tid & 63;
  const int c4 = tid >> 6;              // 0..3
  for (int cc = 0; cc < 8; ++cc) {
    int cpair = cc * 4 + c4;            // 0..31
    const float* xr = x + (((long)(b * C_IN + 2 * cpair) * H_IN) + h) * W_IN + w0;
    float v0 = xr[wl];
    float v1 = xr[(long)H_IN * W_IN + wl];
    unsigned u0 = __builtin_bit_cast(unsigned short, (__bf16)v0);
    unsigned u1 = __builtin_bit_cast(unsigned short, (__bf16)v1);
    tile32[cpair][wl] = u0 | (u1 << 16);
  }
  __syncthreads();
  const int cpair = tid & 31;
  const int ws0   = tid >> 5;           // 0..7
  const long rowb2 = (((long)(b * HP) + h + 1) * HROW) >> 1;   // u32 index
  for (int it = 0; it < 8; ++it) {
    int wloc = it * 8 + ws0;
    int pc   = w0 + wloc + 1;
    xtp32[rowb2 + (pc & 1) * (PLANE >> 1) + (pc >> 1) * 32 + cpair] =
        tile32[cpair][wloc];
  }
}

// w [cout][ci][3][3] f32 -> wt2b [khkw][cout][ci] bf16
__global__ __launch_bounds__(256) void wprep_kernel(
    const float* __restrict__ w, __hip_bfloat16* __restrict__ wt2b) {
  int tid  = blockIdx.x * 256 + threadIdx.x;   // 0 .. 73727
  int khkw = tid >> 13;
  int cout = (tid >> 6) & 127;
  int ci   = tid & 63;
  wt2b[tid] = (__hip_bfloat16)w[(cout * C_IN + ci) * 9 + khkw];
}

// ---------------------------------------------------------------------------
// implicit-GEMM conv: tile 128 pixels x 128 cout, K=576, BK=64 (9 chunks).
// block = 512 thr (8 waves, 4x2): wave tile 32x64, acc[2][4].
// LDS 64KB dbuf -> 2 blocks/CU = 16 waves/CU = 4/SIMD (TLP to hide staging).
// counted vmcnt: 2 chunks in flight (4 loads/thread each), wait vmcnt(4).
// XCD-chunked bijective swizzle: blockIdx%8 = XCD gets contiguous oh.
__global__ __launch_bounds__(512) void conv_gemm_kernel(
    const __hip_bfloat16* __restrict__ xtp,
    const __hip_bfloat16* __restrict__ wt2b,
    const float* __restrict__ bias,
    __hip_bfloat16* __restrict__ g) {
  __shared__ __hip_bfloat16 Abuf[2][8192];
  __shared__ __hip_bfloat16 Bbuf[2][8192];

  const int tid  = threadIdx.x;
  const int lane = tid & 63;
  const int wid  = tid >> 6;                    // 0..7
  const int b0   = blockIdx.x;                  // 0..1023
  const int bid  = (b0 & 7) * 128 + (b0 >> 3);  // XCD-chunked (bijective)
  const int bimg = bid >> 7;
  const int oh   = bid & 127;
  const int wr   = wid >> 1;                    // 0..3 (32-pixel row block)
  const int wc   = wid & 1;                     // 0..1 (64-cout col block)

  f32x4 acc[2][4] = {};

  auto stage = [&](int buf, int t) {
    const int kh = t / 3;
    const int kw = t - kh * 3;
    const long abase = (((long)bimg * HP + (2 * oh + kh)) * 2 + (kw & 1)) * PLANE
                       + ((kw == 2) ? 64 : 0);
    const long bbase = (long)t * 8192;
#pragma unroll
    for (int p = 0; p < 2; ++p) {
      int flat = p * 512 + tid;                   // 0..1023
      int row  = flat >> 3;                       // 0..127
      int cs   = (flat & 7) ^ (row & 7);          // inverse-swizzled src chunk
      long soff = (long)row * 64 + cs * 8;
      char* dA = (char*)&Abuf[buf][0] + flat * 16;
      char* dB = (char*)&Bbuf[buf][0] + flat * 16;
      GLOAD_LDS16(xtp + abase + soff, dA);
      GLOAD_LDS16(wt2b + bbase + soff, dB);
    }
  };

  auto compute = [&](int buf) {
    const int r15 = lane & 15;
    const int kg  = lane >> 4;
#pragma unroll
    for (int h = 0; h < 2; ++h) {
      bf16x8 af[2], bfv[4];
      const int co = h * 4 + kg;                  // 16B slot 0..7
#pragma unroll
      for (int i = 0; i < 2; ++i) {
        int rowa = wr * 32 + i * 16 + r15;
        int ca   = co ^ (rowa & 7);
        af[i] = *(const bf16x8*)((const char*)&Abuf[buf][0] + rowa * 128 + ca * 16);
      }
#pragma unroll
      for (int n = 0; n < 4; ++n) {
        int rowb = wc * 64 + n * 16 + r15;
        int cb   = co ^ (rowb & 7);
        bfv[n] = *(const bf16x8*)((const char*)&Bbuf[buf][0] + rowb * 128 + cb * 16);
      }
#pragma unroll
      for (int i = 0; i < 2; ++i)
#pragma unroll
        for (int n = 0; n < 4; ++n)
          acc[i][n] = __builtin_amdgcn_mfma_f32_16x16x32_bf16(af[i], bfv[n],
                                                              acc[i][n], 0, 0, 0);
    }
  };

  stage(0, 0);                                   // 4 loads/thread
  stage(1, 1);                                   // 8 outstanding
#pragma unroll 1
  for (int t = 0; t < 9; ++t) {
    if (t < 8) {
      asm volatile("s_waitcnt vmcnt(4)" ::: "memory");   // chunk t landed
    } else {
      asm volatile("s_waitcnt vmcnt(0)" ::: "memory");
    }
    __builtin_amdgcn_sched_barrier(0);
    __builtin_amdgcn_s_barrier();                 // all waves' chunk-t in LDS
    compute(t & 1);
    __builtin_amdgcn_s_barrier();                 // all reads of this buf done
    __builtin_amdgcn_sched_barrier(0);
    if (t + 2 < 9) stage(t & 1, t + 2);           // refill freed buffer
  }

  // epilogue: bias+relu -> LDS bf16 C-tile -> coalesced dwordx4 stores
  __hip_bfloat16* ct = &Abuf[0][0];               // 32KB = both A buffers
  const int col0 = wc * 64 + (lane & 15);
  float bn[4];
  for (int n = 0; n < 4; ++n) bn[n] = bias[col0 + n * 16];
  for (int i = 0; i < 2; ++i) {
    int row0 = wr * 32 + i * 16 + (lane >> 4) * 4;
    for (int n = 0; n < 4; ++n) {
      int cout = col0 + n * 16;
      for (int r = 0; r < 4; ++r) {
        float v = fmaxf(acc[i][n][r] + bn[n], 0.0f);
        ct[(row0 + r) * 128 + cout] = (__hip_bfloat16)v;
      }
    }
  }
  __syncthreads();
  const long gbase = (long)bid * (128 * 128);
  for (int it = 0; it < 4; ++it) {
    int flat = it * 512 + tid;
    bf16x8 v = *(const bf16x8*)((const char*)ct + flat * 16);
    *(bf16x8*)(g + gbase + (long)flat * 8) = v;
  }
}

// ---------------------------------------------------------------------------
// fused two-level CSR segment-max + add.
// one wave per point n. Batch-load 64 indices coalesced; each lane reads
// 16B (8 channels) so one load covers 4 rows; 4 quads (16 rows) in flight.
__global__ __launch_bounds__(256) void gather_max_add_kernel(
    const __hip_bfloat16* __restrict__ g,
    const float* __restrict__ x3d,
    const int* __restrict__ fm_idx,
    const int* __restrict__ a_ptr,
    const int* __restrict__ v_ptr,
    float* __restrict__ out) {
  const int lane = threadIdx.x & 63;
  const int n    = blockIdx.x * 4 + (threadIdx.x >> 6);

  const int v0 = v_ptr[n];
  const int v1 = v_ptr[n + 1];
  const int r0 = a_ptr[v0];
  const int r1 = a_ptr[v1];
  const int len = r1 - r0;

  const int sub  = lane >> 4;     // row-in-quad 0..3
  const int ch16 = lane & 15;     // 16B chunk = channels ch16*8 .. +7

  // hoist x3d read (overlaps with gather latency)
  const float4* x4 = (const float4*)x3d;
  const long b0 = (long)n * 32 + ch16 * 2;
  float4 xa, xb;
  if (sub == 0) { xa = x4[b0]; xb = x4[b0 + 1]; }

  float m[8];
#pragma unroll
  for (int k = 0; k < 8; ++k) m[k] = 0.0f;

  const uint4* gp = (const uint4*)g;

  for (int base = 0; base < len; base += 64) {
    int nb = len - base;
    if (nb > 64) nb = 64;
    int li = base + lane;
    if (li >= len) li = len - 1;
    const int idx_l = fm_idx[r0 + li];           // one coalesced batch load

    for (int j = 0; j < nb; j += 16) {
      int r[4];
#pragma unroll
      for (int q = 0; q < 4; ++q) {
        int rr = j + q * 4 + sub;
        r[q] = (rr >= nb) ? nb - 1 : rr;         // duplicate row: max-safe
      }
      uint4 v[4];
#pragma unroll
      for (int q = 0; q < 4; ++q) {
        int iq = __shfl(idx_l, r[q]);
        v[q] = gp[(long)iq * 16 + ch16];
      }
#pragma unroll
      for (int q = 0; q < 4; ++q) {
        const unsigned* u = (const unsigned*)&v[q];
#pragma unroll
        for (int w = 0; w < 4; ++w) {
          m[2 * w]     = fmaxf(m[2 * w],     __uint_as_float(u[w] << 16));
          m[2 * w + 1] = fmaxf(m[2 * w + 1], __uint_as_float(u[w] & 0xffff0000u));
        }
      }
    }
  }

  // combine the 4 row-subgroups (same channels live at lane^16, lane^32)
#pragma unroll
  for (int k = 0; k < 8; ++k) {
    m[k] = fmaxf(m[k], __shfl_xor(m[k], 16));
    m[k] = fmaxf(m[k], __shfl_xor(m[k], 32));
  }

  if (sub == 0) {
    float4* o4 = (float4*)out;
    float4 oa, ob;
    oa.x = xa.x + m[0]; oa.y = xa.y + m[1]; oa.z = xa.z + m[2]; oa.w = xa.w + m[3];
    ob.x = xb.x + m[4]; ob.y = xb.y + m[5]; ob.z = xb.z + m[6]; ob.w = xb.w + m[7];
    o4[b0]     = oa;
    o4[b0 + 1] = ob;
  }
}

// ---------------------------------------------------------------------------
extern "C" void kernel_launch(void* const* d_in, const int* in_sizes, int n_in,
                              void* d_out, int out_size, void* d_ws, size_t ws_size,
                              hipStream_t stream) {
  const float* x     = (const float*)d_in[0];
  const float* w     = (const float*)d_in[1];
  const float* bias  = (const float*)d_in[2];
  const float* x3d   = (const float*)d_in[3];
  const int*   fmidx = (const int*)d_in[4];
  const int*   aptr  = (const int*)d_in[5];
  const int*   vptr  = (const int*)d_in[6];
  float* out = (float*)d_out;

  char* ws = (char*)d_ws;
  __hip_bfloat16* xtp  = (__hip_bfloat16*)(ws + XTP_OFF);
  __hip_bfloat16* g    = (__hip_bfloat16*)(ws + G_OFF);
  __hip_bfloat16* wt2b = (__hip_bfloat16*)(ws + WT2_OFF);

  hipLaunchKernelGGL(halo_zero_kernel, dim3(HP, B_IMG), dim3(256), 0, stream,
                     xtp);
  hipLaunchKernelGGL(transpose_x_kernel, dim3(W_IN / 64, H_IN, B_IMG), dim3(256),
                     0, stream, x, (unsigned*)xtp);
  hipLaunchKernelGGL(wprep_kernel, dim3((C_OUT * KTOT) / 256), dim3(256), 0,
                     stream, w, wt2b);
  hipLaunchKernelGGL(conv_gemm_kernel, dim3(NPIX / 128), dim3(512), 0, stream,
                     xtp, wt2b, bias, g);
  hipLaunchKernelGGL(gather_max_add_kernel, dim3(N_PTS / 4), dim3(256), 0,
                     stream, g, x3d, fmidx, aptr, vptr, out);
}